// Round 8
// baseline (253.024 us; speedup 1.0000x reference)
//
#include <hip/hip_runtime.h>

// out[n,k] = <Cmat[k], project[n]> + d[k]   (pipeline is fully linear in project)
// Cmat[k][c*196+hw] = sum_ji R[ji,hw] * Bmat[(k,ji)][c],  Bmat = WH·w3·w2·w1
// Prep: level1 {Y=w2·w1, T=WH·w3} in one launch (K-split x2), level2 Bmat=T·Y.
// k_main: persistent 1024 blocks, 4 blocks/CU, Cmat slice (40KB) in LDS,
//         4 n per wave, swizzled LDS-transpose epilogue (conflict-free).
//
// ws layout (floats):
//   WH   [490][512]   off 0
//   Ya   [512][512]   off 250880
//   Yb   [512][512]   off 513024
//   Ta   [490][512]   off 775168
//   Tb   [490][512]   off 1026048
//   Bma  [490][512]   off 1276928
//   Bmb  [490][512]   off 1527808
//   Cm   [10][CHW]    off 1778688
//   u2   [512]        off 2782208
//   vv   [512]        off 2782720
//   dpart[10][8]      off 2783232
//   part [98][512][10] off 2783312

#define CHW 100352   // 512*196
#define CHW4 25088
#define NSEG 98
#define SEG 1024
#define SEGV 256
#define NITEM 3136   // 32 g-groups(16 n) x 98 s
#define STEP 1.8571428571428572f  // 13/7

__device__ __forceinline__ float edge_w(int p, float s, int lim) {
    float f = floorf(s);
    float wfrac = s - f;
    int a = (int)f;
    int b = a + 1;
    a = min(max(a, 0), lim); b = min(max(b, 0), lim);
    float c = 0.f;
    if (p == a) c += 1.f - wfrac;
    if (p == b) c += wfrac;
    return c;
}

// WH[r][q] = wh[k][q*49 + ji],  r = k*49 + ji
__global__ void k_whT(const float* __restrict__ w_note, const float* __restrict__ w_reg,
                      float* __restrict__ WH) {
    int r = blockIdx.x;      // 0..489
    int q = threadIdx.x;     // 0..511
    int k = r / 49, ji = r % 49;
    const float* wh = (k < 2) ? (w_note + k * 25088) : (w_reg + (k - 2) * 25088);
    WH[(size_t)r * 512 + q] = wh[q * 49 + ji];
}

// Level 1: 4 sub-mms in one launch. half 0/1: Y=w2·w1 K-halves; 2/3: T=WH·w3.
// 32x32 tile, 2x2/thread, transposed-A LDS, float2 reads, K=256 per half.
__global__ __launch_bounds__(256) void k_lvl1(const float* __restrict__ w1,
                                              const float* __restrict__ w2,
                                              const float* __restrict__ w3,
                                              const float* __restrict__ WH,
                                              float* __restrict__ Ya, float* __restrict__ Yb,
                                              float* __restrict__ Ta, float* __restrict__ Tb) {
    __shared__ float As[32][34];   // [kk][row]
    __shared__ float Bs[32][36];   // [kk][col]
    int bx = blockIdx.x;
    int half = bx >> 8;
    int t = bx & 255;
    int bxc = t & 15, byr = t >> 4;
    const float* A; const float* B; float* C; int M; int k0;
    if (half == 0)      { A = w2; B = w1; C = Ya; M = 512; k0 = 0;   }
    else if (half == 1) { A = w2; B = w1; C = Yb; M = 512; k0 = 256; }
    else if (half == 2) { A = WH; B = w3; C = Ta; M = 490; k0 = 0;   }
    else                { A = WH; B = w3; C = Tb; M = 490; k0 = 256; }
    int tid = threadIdx.x;
    int ar = tid >> 3, ac = (tid & 7) << 2;
    int ty = tid >> 4, tx = tid & 15;
    float a00 = 0.f, a01 = 0.f, a10 = 0.f, a11 = 0.f;
    for (int ks = 0; ks < 256; ks += 32) {
        int gr = byr * 32 + ar;
        float4 av = make_float4(0.f, 0.f, 0.f, 0.f);
        if (gr < M) av = *(const float4*)&A[(size_t)gr * 512 + k0 + ks + ac];
        As[ac + 0][ar] = av.x; As[ac + 1][ar] = av.y;
        As[ac + 2][ar] = av.z; As[ac + 3][ar] = av.w;
        float4 bv = *(const float4*)&B[(size_t)(k0 + ks + ar) * 512 + bxc * 32 + ac];
        *(float4*)&Bs[ar][ac] = bv;
        __syncthreads();
        #pragma unroll
        for (int kk = 0; kk < 32; ++kk) {
            float2 a = *(const float2*)&As[kk][ty * 2];
            float2 b = *(const float2*)&Bs[kk][tx * 2];
            a00 += a.x * b.x; a01 += a.x * b.y;
            a10 += a.y * b.x; a11 += a.y * b.y;
        }
        __syncthreads();
    }
    int r0 = byr * 32 + ty * 2, c0 = bxc * 32 + tx * 2;
    if (r0 < M)     { C[(size_t)r0 * 512 + c0] = a00; C[(size_t)r0 * 512 + c0 + 1] = a01; }
    if (r0 + 1 < M) { C[(size_t)(r0 + 1) * 512 + c0] = a10; C[(size_t)(r0 + 1) * 512 + c0 + 1] = a11; }
}

// Level 2: Bmat = (Ta+Tb)·(Ya+Yb), K-split x2 (half 0 -> Bma, 1 -> Bmb). M=490.
__global__ __launch_bounds__(256) void k_lvl2(const float* __restrict__ Ya,
                                              const float* __restrict__ Yb,
                                              const float* __restrict__ Ta,
                                              const float* __restrict__ Tb,
                                              float* __restrict__ Bma, float* __restrict__ Bmb) {
    __shared__ float As[32][34];
    __shared__ float Bs[32][36];
    int bx = blockIdx.x;
    int half = bx >> 8;
    int t = bx & 255;
    int bxc = t & 15, byr = t >> 4;
    float* C = half ? Bmb : Bma;
    int k0 = half ? 256 : 0;
    const int M = 490;
    int tid = threadIdx.x;
    int ar = tid >> 3, ac = (tid & 7) << 2;
    int ty = tid >> 4, tx = tid & 15;
    float a00 = 0.f, a01 = 0.f, a10 = 0.f, a11 = 0.f;
    for (int ks = 0; ks < 256; ks += 32) {
        int gr = byr * 32 + ar;
        float4 av = make_float4(0.f, 0.f, 0.f, 0.f);
        if (gr < M) {
            size_t ai = (size_t)gr * 512 + k0 + ks + ac;
            float4 v1 = *(const float4*)&Ta[ai];
            float4 v2 = *(const float4*)&Tb[ai];
            av = make_float4(v1.x + v2.x, v1.y + v2.y, v1.z + v2.z, v1.w + v2.w);
        }
        As[ac + 0][ar] = av.x; As[ac + 1][ar] = av.y;
        As[ac + 2][ar] = av.z; As[ac + 3][ar] = av.w;
        size_t bi = (size_t)(k0 + ks + ar) * 512 + bxc * 32 + ac;
        float4 b1v = *(const float4*)&Ya[bi];
        float4 b2v = *(const float4*)&Yb[bi];
        *(float4*)&Bs[ar][ac] = make_float4(b1v.x + b2v.x, b1v.y + b2v.y,
                                            b1v.z + b2v.z, b1v.w + b2v.w);
        __syncthreads();
        #pragma unroll
        for (int kk = 0; kk < 32; ++kk) {
            float2 a = *(const float2*)&As[kk][ty * 2];
            float2 b = *(const float2*)&Bs[kk][tx * 2];
            a00 += a.x * b.x; a01 += a.x * b.y;
            a10 += a.y * b.x; a11 += a.y * b.y;
        }
        __syncthreads();
    }
    int r0 = byr * 32 + ty * 2, c0 = bxc * 32 + tx * 2;
    if (r0 < M)     { C[(size_t)r0 * 512 + c0] = a00; C[(size_t)r0 * 512 + c0 + 1] = a01; }
    if (r0 + 1 < M) { C[(size_t)(r0 + 1) * 512 + c0] = a10; C[(size_t)(r0 + 1) * 512 + c0 + 1] = a11; }
}

// Cm[k*CHW + c*196 + hw] = sum_ji cy*cx * (Bma+Bmb)[(k*49+ji)*512 + c]
__global__ void k_spread2(const float* __restrict__ Bma, const float* __restrict__ Bmb,
                          float* __restrict__ Cm) {
    int c = blockIdx.x;      // 0..511
    int k = blockIdx.y;      // 0..9
    int hw = threadIdx.x;    // 0..195
    int h = hw / 14, w = hw % 14;
    const float base = STEP * 0.5f - 0.5f;
    float acc = 0.f;
    for (int j = 0; j < 7; ++j) {
        float cy = edge_w(h, base + j * STEP, 13);
        if (cy == 0.f) continue;
        for (int i = 0; i < 7; ++i) {
            float cx = edge_w(w, base + i * STEP, 13);
            if (cx != 0.f) {
                size_t idx = (size_t)(k * 49 + j * 7 + i) * 512 + c;
                acc += cy * cx * (Bma[idx] + Bmb[idx]);
            }
        }
    }
    Cm[(size_t)k * CHW + c * 196 + hw] = acc;
}

// u2 = b2 + w2·b1
__global__ void k_mv1(const float* __restrict__ w2, const float* __restrict__ b1,
                      const float* __restrict__ b2, float* __restrict__ u2) {
    int o = blockIdx.x;
    int l = threadIdx.x;  // 64
    float s = 0.f;
    for (int i = l; i < 512; i += 64) s += w2[(size_t)o * 512 + i] * b1[i];
    for (int off = 32; off; off >>= 1) s += __shfl_down(s, off);
    if (l == 0) u2[o] = b2[o] + s;
}

// vv = b3 + w3·u2
__global__ void k_mv2(const float* __restrict__ w3, const float* __restrict__ u2,
                      const float* __restrict__ b3, float* __restrict__ vv) {
    int o = blockIdx.x;
    int l = threadIdx.x;  // 64
    float s = 0.f;
    for (int i = l; i < 512; i += 64) s += w3[(size_t)o * 512 + i] * u2[i];
    for (int off = 32; off; off >>= 1) s += __shfl_down(s, off);
    if (l == 0) vv[o] = b3[o] + s;
}

// dpart[k][b] = partial of sum_i wh[k][i] * vv[i/49]
__global__ void k_dvec(const float* __restrict__ w_note, const float* __restrict__ w_reg,
                       const float* __restrict__ vv, float* __restrict__ dpart) {
    int k = blockIdx.x;   // 10
    int b = blockIdx.y;   // 8
    int t = threadIdx.x;  // 256
    const float* wh = (k < 2) ? (w_note + k * 25088) : (w_reg + (k - 2) * 25088);
    float s = 0.f;
    for (int i = b * 256 + t; i < 25088; i += 2048) s += wh[i] * vv[i / 49];
    __shared__ float red[256];
    red[t] = s;
    __syncthreads();
    for (int off = 128; off; off >>= 1) {
        if (t < off) red[t] += red[t + off];
        __syncthreads();
    }
    if (t == 0) dpart[k * 8 + b] = red[0];
}

// Persistent k_main: 1024 blocks x 256 thr (4 blocks/CU), items = (g,s) g-major.
// Per item: stage Cmat slice s (40 KB), 4 waves x 4 n, 4 windows, swizzled
// LDS-transpose epilogue reusing cml (conflict-free both sides).
__global__ __launch_bounds__(256, 4) void k_main(const float* __restrict__ proj,
                                                 const float* __restrict__ Cmat,
                                                 float* __restrict__ part) {
    __shared__ float4 cml[10 * SEGV];   // 40,960 B
    float* red = (float*)cml;
    int tid = threadIdx.x;
    int wv = tid >> 6, lane = tid & 63;
    const float4* cg = (const float4*)Cmat;
    const float4* pg = (const float4*)proj;
    for (int m = blockIdx.x; m < NITEM; m += 1024) {
        int g = m / NSEG;
        int s = m - g * NSEG;
        #pragma unroll
        for (int i = 0; i < 10; ++i)
            cml[i * 256 + tid] = cg[(size_t)i * CHW4 + s * SEGV + tid];
        __syncthreads();

        int n0 = g * 16 + wv * 4;
        const float4* p0 = pg + (size_t)n0 * CHW4 + s * SEGV + lane;
        const float4* p1 = p0 + CHW4;
        const float4* p2 = p1 + CHW4;
        const float4* p3 = p2 + CHW4;
        float acc[4][10];
        #pragma unroll
        for (int j = 0; j < 4; ++j)
            #pragma unroll
            for (int k = 0; k < 10; ++k) acc[j][k] = 0.f;

        float4 pa = p0[0], pb = p1[0], pc = p2[0], pd = p3[0];
        #pragma unroll 1
        for (int it = 0; it < 4; ++it) {
            float4 na, nb, nc, nd;
            if (it < 3) {
                na = p0[(it + 1) * 64]; nb = p1[(it + 1) * 64];
                nc = p2[(it + 1) * 64]; nd = p3[(it + 1) * 64];
            }
            #pragma unroll
            for (int k = 0; k < 10; ++k) {
                float4 c = cml[k * 256 + it * 64 + lane];
                acc[0][k] += pa.x * c.x + pa.y * c.y + pa.z * c.z + pa.w * c.w;
                acc[1][k] += pb.x * c.x + pb.y * c.y + pb.z * c.z + pb.w * c.w;
                acc[2][k] += pc.x * c.x + pc.y * c.y + pc.z * c.z + pc.w * c.w;
                acc[3][k] += pd.x * c.x + pd.y * c.y + pd.z * c.z + pd.w * c.w;
            }
            if (it < 3) { pa = na; pb = nb; pc = nc; pd = nd; }
        }

        __syncthreads();   // cml reads done; safe to overwrite as red
        #pragma unroll
        for (int j = 0; j < 4; ++j)
            #pragma unroll
            for (int k = 0; k < 10; ++k) {
                int row = (wv * 4 + j) * 10 + k;
                red[row * 64 + ((lane + row) & 63)] = acc[j][k];
            }
        __syncthreads();
        if (tid < 160) {
            float s0 = 0.f, s1 = 0.f, s2 = 0.f, s3 = 0.f;
            #pragma unroll
            for (int i = 0; i < 64; i += 4) {
                s0 += red[tid * 64 + ((tid + i + 0) & 63)];
                s1 += red[tid * 64 + ((tid + i + 1) & 63)];
                s2 += red[tid * 64 + ((tid + i + 2) & 63)];
                s3 += red[tid * 64 + ((tid + i + 3) & 63)];
            }
            part[((size_t)s * 512 + g * 16 + tid / 10) * 10 + (tid % 10)] =
                (s0 + s1) + (s2 + s3);
        }
        __syncthreads();   // red reads done; safe for next item's stage
    }
}

__global__ void k_reduce(const float* __restrict__ part,
                         const float* __restrict__ dpart,
                         const float* __restrict__ b_note, const float* __restrict__ b_reg,
                         float* __restrict__ out) {
    int idx = blockIdx.x * 256 + threadIdx.x;  // 0..5119
    int n = idx / 10, k = idx % 10;
    float s = (k < 2) ? b_note[k] : b_reg[k - 2];
    for (int b = 0; b < 8; ++b) s += dpart[k * 8 + b];
    for (int seg = 0; seg < NSEG; ++seg) s += part[((size_t)seg * 512 + n) * 10 + k];
    if (k < 2) out[n * 2 + k] = s;
    else       out[1024 + n * 8 + (k - 2)] = s;
}

extern "C" void kernel_launch(void* const* d_in, const int* in_sizes, int n_in,
                              void* d_out, int out_size, void* d_ws, size_t ws_size,
                              hipStream_t stream) {
    const float* proj   = (const float*)d_in[0];
    const float* w1     = (const float*)d_in[1];
    const float* b1     = (const float*)d_in[2];
    const float* w2     = (const float*)d_in[3];
    const float* b2     = (const float*)d_in[4];
    const float* w3     = (const float*)d_in[5];
    const float* b3     = (const float*)d_in[6];
    const float* w_note = (const float*)d_in[7];
    const float* b_note = (const float*)d_in[8];
    const float* w_reg  = (const float*)d_in[9];
    const float* b_reg  = (const float*)d_in[10];

    float* ws    = (float*)d_ws;
    float* WH    = ws;
    float* Ya    = WH + 250880;
    float* Yb    = Ya + 262144;
    float* Ta    = Yb + 262144;
    float* Tb    = Ta + 250880;
    float* Bma   = Tb + 250880;
    float* Bmb   = Bma + 250880;
    float* Cm    = Bmb + 250880;
    float* u2    = Cm + 1003520;
    float* vv    = u2 + 512;
    float* dpart = vv + 512;
    float* part  = dpart + 80;
    float* out   = (float*)d_out;

    k_whT<<<490, 512, 0, stream>>>(w_note, w_reg, WH);
    k_lvl1<<<1024, 256, 0, stream>>>(w1, w2, w3, WH, Ya, Yb, Ta, Tb);
    k_lvl2<<<512, 256, 0, stream>>>(Ya, Yb, Ta, Tb, Bma, Bmb);
    k_spread2<<<dim3(512, 10), 196, 0, stream>>>(Bma, Bmb, Cm);
    k_mv1<<<512, 64, 0, stream>>>(w2, b1, b2, u2);
    k_mv2<<<512, 64, 0, stream>>>(w3, u2, b3, vv);
    k_dvec<<<dim3(10, 8), 256, 0, stream>>>(w_note, w_reg, vv, dpart);
    k_main<<<1024, 256, 0, stream>>>(proj, Cm, part);
    k_reduce<<<20, 256, 0, stream>>>(part, dpart, b_note, b_reg, out);
}

// Round 9
// 151.725 us; speedup vs baseline: 1.6677x; 1.6677x over previous
//
#include <hip/hip_runtime.h>

// out[n,k] = <Cmat[k], project[n]> + d[k]   (pipeline is fully linear in project)
// Cmat[k][c*196+hw] = sum_ji R[ji,hw] * Bmat[(k,ji)][c],  Bmat = WH·(w3·w2·w1)
//
// k_main: persistent 1024 blocks (4/CU via 40KB LDS), Cmat slice in LDS,
// 4 waves x 4 n per wave, swizzled LDS-transpose epilogue (conflict-free).
// NO occupancy arg in launch_bounds: round-8 showed (256,4) forces VGPR=64
// and spills the 90-reg live set (222 MB scratch writes). LDS alone pins
// occupancy at 4 blocks/CU; compiler then allocates ~110 VGPR, no spill.
//
// ws layout (floats):
//   W23   [512][512]     off 0
//   W123  [512][512]     off 262144
//   WH    [490][512]     off 524288
//   Bmat  [490][512]     off 775168
//   Cm    [10][CHW]      off 1026048
//   vvec  [512]          off 2029568
//   dpart [10][8]        off 2030080
//   part  [98][512][10]  off 2030160

#define CHW 100352   // 512*196
#define CHW4 25088
#define NSEG 98
#define SEG 1024
#define SEGV 256
#define NITEM 3136   // 32 g-groups(16 n) x 98 s
#define STEP 1.8571428571428572f  // 13/7

__device__ __forceinline__ float edge_w(int p, float s, int lim) {
    float f = floorf(s);
    float wfrac = s - f;
    int a = (int)f;
    int b = a + 1;
    a = min(max(a, 0), lim); b = min(max(b, 0), lim);
    float c = 0.f;
    if (p == a) c += 1.f - wfrac;
    if (p == b) c += wfrac;
    return c;
}

// C[M x 512] = A[M x 512] * B[512 x 512]; 32x32 tile per block, thread = 2x2.
__global__ __launch_bounds__(256) void k_mm32(const float* __restrict__ A,
                                              const float* __restrict__ B,
                                              float* __restrict__ C, int M) {
    __shared__ float As[32][36];
    __shared__ float Bs[32][36];
    int bx = blockIdx.x, by = blockIdx.y;
    int tid = threadIdx.x;
    int lr = tid >> 3;          // 0..31
    int lc = (tid & 7) << 2;    // 0,4,..,28
    int tx = tid & 15, ty = tid >> 4;
    float a00 = 0.f, a01 = 0.f, a10 = 0.f, a11 = 0.f;
    for (int kc = 0; kc < 512; kc += 32) {
        int gr = by * 32 + lr;
        float4 av = make_float4(0.f, 0.f, 0.f, 0.f);
        if (gr < M) av = *(const float4*)&A[(size_t)gr * 512 + kc + lc];
        *(float4*)&As[lr][lc] = av;
        float4 bv = *(const float4*)&B[(size_t)(kc + lr) * 512 + bx * 32 + lc];
        *(float4*)&Bs[lr][lc] = bv;
        __syncthreads();
        #pragma unroll
        for (int kk = 0; kk < 32; ++kk) {
            float b0 = Bs[kk][tx * 2], b1 = Bs[kk][tx * 2 + 1];
            float x0 = As[ty * 2][kk], x1 = As[ty * 2 + 1][kk];
            a00 += x0 * b0; a01 += x0 * b1;
            a10 += x1 * b0; a11 += x1 * b1;
        }
        __syncthreads();
    }
    int r0 = by * 32 + ty * 2, c0 = bx * 32 + tx * 2;
    if (r0 < M)     { C[(size_t)r0 * 512 + c0] = a00; C[(size_t)r0 * 512 + c0 + 1] = a01; }
    if (r0 + 1 < M) { C[(size_t)(r0 + 1) * 512 + c0] = a10; C[(size_t)(r0 + 1) * 512 + c0 + 1] = a11; }
}

// WH[r][q] = wh[k][q*49 + ji],  r = k*49 + ji
__global__ void k_whT(const float* __restrict__ w_note, const float* __restrict__ w_reg,
                      float* __restrict__ WH) {
    int r = blockIdx.x;      // 0..489
    int q = threadIdx.x;     // 0..511
    int k = r / 49, ji = r % 49;
    const float* wh = (k < 2) ? (w_note + k * 25088) : (w_reg + (k - 2) * 25088);
    WH[(size_t)r * 512 + q] = wh[q * 49 + ji];
}

// Cm[k*CHW + c*196 + hw] = sum_ji cy(j,h)*cx(i,w) * Bmat[(k*49+ji)*512 + c]
__global__ void k_spread2(const float* __restrict__ Bmat, float* __restrict__ Cm) {
    int c = blockIdx.x;      // 0..511
    int k = blockIdx.y;      // 0..9
    int hw = threadIdx.x;    // 0..195
    int h = hw / 14, w = hw % 14;
    const float base = STEP * 0.5f - 0.5f;
    float acc = 0.f;
    for (int j = 0; j < 7; ++j) {
        float cy = edge_w(h, base + j * STEP, 13);
        if (cy == 0.f) continue;
        for (int i = 0; i < 7; ++i) {
            float cx = edge_w(w, base + i * STEP, 13);
            if (cx != 0.f) acc += cy * cx * Bmat[(size_t)(k * 49 + j * 7 + i) * 512 + c];
        }
    }
    Cm[(size_t)k * CHW + c * 196 + hw] = acc;
}

// vvec[q] = b3[q] + sum_p w3[q][p]*b2[p] + sum_o W23[q][o]*b1[o]
__global__ void k_bvec(const float* __restrict__ w3, const float* __restrict__ W23,
                       const float* __restrict__ b1, const float* __restrict__ b2,
                       const float* __restrict__ b3, float* __restrict__ vvec) {
    int o = blockIdx.x;
    int l = threadIdx.x;  // 64
    float s = 0.f;
    for (int i = l; i < 512; i += 64)
        s += w3[o * 512 + i] * b2[i] + W23[o * 512 + i] * b1[i];
    for (int off = 32; off; off >>= 1) s += __shfl_down(s, off);
    if (l == 0) vvec[o] = b3[o] + s;
}

// dpart[k][b] = partial of sum_i wh[k][i] * vvec[i/49]
__global__ void k_dvec(const float* __restrict__ w_note, const float* __restrict__ w_reg,
                       const float* __restrict__ vvec, float* __restrict__ dpart) {
    int k = blockIdx.x;   // 10
    int b = blockIdx.y;   // 8
    int t = threadIdx.x;  // 256
    const float* wh = (k < 2) ? (w_note + k * 25088) : (w_reg + (k - 2) * 25088);
    float s = 0.f;
    for (int i = b * 256 + t; i < 25088; i += 2048) s += wh[i] * vvec[i / 49];
    __shared__ float red[256];
    red[t] = s;
    __syncthreads();
    for (int off = 128; off; off >>= 1) {
        if (t < off) red[t] += red[t + off];
        __syncthreads();
    }
    if (t == 0) dpart[k * 8 + b] = red[0];
}

// Persistent k_main: 1024 blocks x 256 thr, items = (g,s) g-major.
// Per item: stage Cmat slice s (40 KB), 4 waves x 4 n, 4 windows, swizzled
// LDS-transpose epilogue reusing cml (conflict-free both sides).
__global__ __launch_bounds__(256) void k_main(const float* __restrict__ proj,
                                              const float* __restrict__ Cmat,
                                              float* __restrict__ part) {
    __shared__ float4 cml[10 * SEGV];   // 40,960 B
    float* red = (float*)cml;
    int tid = threadIdx.x;
    int wv = tid >> 6, lane = tid & 63;
    const float4* cg = (const float4*)Cmat;
    const float4* pg = (const float4*)proj;
    for (int m = blockIdx.x; m < NITEM; m += 1024) {
        int g = m / NSEG;
        int s = m - g * NSEG;
        #pragma unroll
        for (int i = 0; i < 10; ++i)
            cml[i * 256 + tid] = cg[(size_t)i * CHW4 + s * SEGV + tid];
        __syncthreads();

        int n0 = g * 16 + wv * 4;
        const float4* p0 = pg + (size_t)n0 * CHW4 + s * SEGV + lane;
        const float4* p1 = p0 + CHW4;
        const float4* p2 = p1 + CHW4;
        const float4* p3 = p2 + CHW4;
        float acc[4][10];
        #pragma unroll
        for (int j = 0; j < 4; ++j)
            #pragma unroll
            for (int k = 0; k < 10; ++k) acc[j][k] = 0.f;

        float4 pa = p0[0], pb = p1[0], pc = p2[0], pd = p3[0];
        #pragma unroll 1
        for (int it = 0; it < 4; ++it) {
            float4 na, nb, nc, nd;
            if (it < 3) {
                na = p0[(it + 1) * 64]; nb = p1[(it + 1) * 64];
                nc = p2[(it + 1) * 64]; nd = p3[(it + 1) * 64];
            }
            #pragma unroll
            for (int k = 0; k < 10; ++k) {
                float4 c = cml[k * 256 + it * 64 + lane];
                acc[0][k] += pa.x * c.x + pa.y * c.y + pa.z * c.z + pa.w * c.w;
                acc[1][k] += pb.x * c.x + pb.y * c.y + pb.z * c.z + pb.w * c.w;
                acc[2][k] += pc.x * c.x + pc.y * c.y + pc.z * c.z + pc.w * c.w;
                acc[3][k] += pd.x * c.x + pd.y * c.y + pd.z * c.z + pd.w * c.w;
            }
            if (it < 3) { pa = na; pb = nb; pc = nc; pd = nd; }
        }

        __syncthreads();   // cml reads done; safe to overwrite as red
        #pragma unroll
        for (int j = 0; j < 4; ++j)
            #pragma unroll
            for (int k = 0; k < 10; ++k) {
                int row = (wv * 4 + j) * 10 + k;
                red[row * 64 + ((lane + row) & 63)] = acc[j][k];
            }
        __syncthreads();
        if (tid < 160) {
            float s0 = 0.f, s1 = 0.f, s2 = 0.f, s3 = 0.f;
            #pragma unroll
            for (int i = 0; i < 64; i += 4) {
                s0 += red[tid * 64 + ((tid + i + 0) & 63)];
                s1 += red[tid * 64 + ((tid + i + 1) & 63)];
                s2 += red[tid * 64 + ((tid + i + 2) & 63)];
                s3 += red[tid * 64 + ((tid + i + 3) & 63)];
            }
            part[((size_t)s * 512 + g * 16 + tid / 10) * 10 + (tid % 10)] =
                (s0 + s1) + (s2 + s3);
        }
        __syncthreads();   // red reads done; safe for next item's stage
    }
}

__global__ void k_reduce(const float* __restrict__ part,
                         const float* __restrict__ dpart,
                         const float* __restrict__ b_note, const float* __restrict__ b_reg,
                         float* __restrict__ out) {
    int idx = blockIdx.x * 256 + threadIdx.x;  // 0..5119
    int n = idx / 10, k = idx % 10;
    float s = (k < 2) ? b_note[k] : b_reg[k - 2];
    for (int b = 0; b < 8; ++b) s += dpart[k * 8 + b];
    for (int seg = 0; seg < NSEG; ++seg) s += part[((size_t)seg * 512 + n) * 10 + k];
    if (k < 2) out[n * 2 + k] = s;
    else       out[1024 + n * 8 + (k - 2)] = s;
}

extern "C" void kernel_launch(void* const* d_in, const int* in_sizes, int n_in,
                              void* d_out, int out_size, void* d_ws, size_t ws_size,
                              hipStream_t stream) {
    const float* proj   = (const float*)d_in[0];
    const float* w1     = (const float*)d_in[1];
    const float* b1     = (const float*)d_in[2];
    const float* w2     = (const float*)d_in[3];
    const float* b2     = (const float*)d_in[4];
    const float* w3     = (const float*)d_in[5];
    const float* b3     = (const float*)d_in[6];
    const float* w_note = (const float*)d_in[7];
    const float* b_note = (const float*)d_in[8];
    const float* w_reg  = (const float*)d_in[9];
    const float* b_reg  = (const float*)d_in[10];

    float* ws    = (float*)d_ws;
    float* W23   = ws;
    float* W123  = W23 + 262144;
    float* WH    = W123 + 262144;
    float* Bmat  = WH + 250880;
    float* Cm    = Bmat + 250880;
    float* vvec  = Cm + 1003520;
    float* dpart = vvec + 512;
    float* part  = dpart + 80;
    float* out   = (float*)d_out;

    k_mm32<<<dim3(16, 16), 256, 0, stream>>>(w3, w2, W23, 512);
    k_mm32<<<dim3(16, 16), 256, 0, stream>>>(W23, w1, W123, 512);
    k_whT<<<490, 512, 0, stream>>>(w_note, w_reg, WH);
    k_mm32<<<dim3(16, 16), 256, 0, stream>>>(WH, W123, Bmat, 490);
    k_spread2<<<dim3(512, 10), 196, 0, stream>>>(Bmat, Cm);
    k_bvec<<<512, 64, 0, stream>>>(w3, W23, b1, b2, b3, vvec);
    k_dvec<<<dim3(10, 8), 256, 0, stream>>>(w_note, w_reg, vvec, dpart);
    k_main<<<1024, 256, 0, stream>>>(proj, Cm, part);
    k_reduce<<<20, 256, 0, stream>>>(part, dpart, b_note, b_reg, out);
}